// Round 1
// baseline (14411.223 us; speedup 1.0000x reference)
//
#include <hip/hip_runtime.h>
#include <math.h>

#define B_ 1024
#define T_ 15
#define E_ 128
#define H_ 1024
#define L_ 128
#define V_ 21

__device__ __forceinline__ float sigf(float x) { return 1.0f / (1.0f + expf(-x)); }

// ---------------- generic 128x128x16 fp32 GEMM: C = A @ W^T (+epilogue) ----------------
// A via aload(m, k) -> float4 (k % 4 == 0); W via wload(bm, n, k) -> float4; store via cstore(m,n,v).
// Requires M % 128 == 0, N % 128 == 0, K % 16 == 0.
template <class AL, class WL, class CS>
__global__ __launch_bounds__(256) void gemm128(AL aload, WL wload, CS cstore, int K) {
    constexpr int BM = 128, BN = 128, BK = 16;
    __shared__ float As[BK][BM];
    __shared__ float Ws[BK][BN];
    const int bm = blockIdx.y * BM;
    const int bn = blockIdx.x * BN;
    const int tid = threadIdx.x;
    const int tx = tid & 15, ty = tid >> 4;

    float acc[8][8];
#pragma unroll
    for (int i = 0; i < 8; ++i)
#pragma unroll
        for (int j = 0; j < 8; ++j) acc[i][j] = 0.0f;

    for (int k0 = 0; k0 < K; k0 += BK) {
#pragma unroll
        for (int r = 0; r < 2; ++r) {
            int i = tid + r * 256;          // 0..511
            int m = i >> 2;                 // 0..127
            int kq = (i & 3) * 4;           // 0,4,8,12
            float4 va = aload(bm + m, k0 + kq);
            As[kq + 0][m] = va.x; As[kq + 1][m] = va.y;
            As[kq + 2][m] = va.z; As[kq + 3][m] = va.w;
            float4 vw = wload(bm, bn + m, k0 + kq);
            Ws[kq + 0][m] = vw.x; Ws[kq + 1][m] = vw.y;
            Ws[kq + 2][m] = vw.z; Ws[kq + 3][m] = vw.w;
        }
        __syncthreads();
#pragma unroll
        for (int kk = 0; kk < BK; ++kk) {
            float a[8], w[8];
#pragma unroll
            for (int i = 0; i < 8; ++i) a[i] = As[kk][ty * 8 + i];
#pragma unroll
            for (int j = 0; j < 8; ++j) w[j] = Ws[kk][tx * 8 + j];
#pragma unroll
            for (int i = 0; i < 8; ++i)
#pragma unroll
                for (int j = 0; j < 8; ++j) acc[i][j] += a[i] * w[j];
        }
        __syncthreads();
    }
#pragma unroll
    for (int i = 0; i < 8; ++i)
#pragma unroll
        for (int j = 0; j < 8; ++j) cstore(bm + ty * 8 + i, bn + tx * 8 + j, acc[i][j]);
}

// ---------------- loader / store functors ----------------
struct LdEncA {  // rows 0..1023: fwd [x_t | h_f]; rows 1024..2047: bwd [x_rev_t | h_b]
    const float* xenc; const float* henc; const int* len; int t;
    __device__ float4 operator()(int m, int k) const {
        int dir = m >> 10, b = m & (B_ - 1);
        if (k < E_) {
            int tt = t;
            if (dir) {
                int ri = len[b] - 1 - t;
                tt = ri < 0 ? 0 : (ri > T_ - 1 ? T_ - 1 : ri);
            }
            return *(const float4*)(xenc + ((size_t)b * T_ + tt) * E_ + k);
        }
        return *(const float4*)(henc + (size_t)dir * B_ * H_ + (size_t)b * H_ + (k - E_));
    }
};
struct LdEncW {
    const float* Wih_f; const float* Whh_f; const float* Wih_b; const float* Whh_b;
    __device__ float4 operator()(int bm, int n, int k) const {
        int dir = bm >> 10;
        if (k < E_) {
            const float* W = dir ? Wih_b : Wih_f;
            return *(const float4*)(W + (size_t)n * E_ + k);
        }
        const float* W = dir ? Whh_b : Whh_f;
        return *(const float4*)(W + (size_t)n * H_ + (k - E_));
    }
};
struct StPlain {
    float* out; int ld;
    __device__ void operator()(int m, int n, float v) const { out[(size_t)m * ld + n] = v; }
};
struct LdHidA {  // hidden = [h_f | h_b], K = 2H
    const float* henc;
    __device__ float4 operator()(int m, int k) const {
        int dir = k >= H_;
        return *(const float4*)(henc + (size_t)dir * B_ * H_ + (size_t)m * H_ + (k & (H_ - 1)));
    }
};
struct LdMLW {  // rows 0..127 -> Wm, 128..255 -> Wl (both ld = 2H)
    const float* Wm; const float* Wl;
    __device__ float4 operator()(int bm, int n, int k) const {
        const float* W = (n < L_) ? Wm : Wl;
        int j = (n < L_) ? n : n - L_;
        return *(const float4*)(W + (size_t)j * (2 * H_) + k);
    }
};
struct StML {
    float* ml; const float* bm; const float* bl;
    __device__ void operator()(int m, int n, float v) const {
        float bias = (n < L_) ? bm[n] : bl[n - L_];
        ml[(size_t)m * 256 + n] = v + bias;
    }
};
struct LdRowA {  // contiguous A with leading dim ld
    const float* p; int ld;
    __device__ float4 operator()(int m, int k) const { return *(const float4*)(p + (size_t)m * ld + k); }
};
struct LdRowW {  // contiguous W with leading dim ld
    const float* p; int ld;
    __device__ float4 operator()(int bm, int n, int k) const { return *(const float4*)(p + (size_t)n * ld + k); }
};
struct StBias {
    float* out; const float* bias; int ld;
    __device__ void operator()(int m, int n, float v) const { out[(size_t)m * ld + n] = v + bias[n]; }
};
struct StBiasRelu {
    float* out; const float* bias; int ld;
    __device__ void operator()(int m, int n, float v) const {
        out[(size_t)m * ld + n] = fmaxf(v + bias[n], 0.0f);
    }
};
struct LdDecA {  // [x_dec_t | h_dec]
    const float* emb; const int* tokens; const float* h; int t;
    __device__ float4 operator()(int m, int k) const {
        if (k < E_) {
            if (t == 0) return make_float4(0.f, 0.f, 0.f, 0.f);
            int tok = tokens[(size_t)m * T_ + (t - 1)];
            return *(const float4*)(emb + (size_t)tok * E_ + k);
        }
        return *(const float4*)(h + (size_t)m * H_ + (k - E_));
    }
};
struct LdDecW {  // stacked [Wi; Wo; Wf; Wg], each (H, E+H)
    const float* Wi; const float* Wo; const float* Wf; const float* Wg;
    __device__ float4 operator()(int bm, int n, int k) const {
        int g = n >> 10, j = n & (H_ - 1);
        const float* W = (g == 0) ? Wi : (g == 1) ? Wo : (g == 2) ? Wf : Wg;
        return *(const float4*)(W + (size_t)j * (E_ + H_) + k);
    }
};
struct StDecG {
    float* G; const float* bi; const float* bo; const float* bfo; const float* bg;
    __device__ void operator()(int m, int n, float v) const {
        int g = n >> 10, j = n & (H_ - 1);
        const float* bb = (g == 0) ? bi : (g == 1) ? bo : (g == 2) ? bfo : bg;
        G[(size_t)m * 4096 + n] = v + bb[j];
    }
};

// ---------------- elementwise / reduction kernels ----------------
__global__ void init_zero(float* henc, float* cenc, float* cdec, float* accs) {
    int i = blockIdx.x * 256 + threadIdx.x;
    if (i < 2 * B_ * H_) { henc[i] = 0.0f; cenc[i] = 0.0f; }
    if (i < B_ * H_) cdec[i] = 0.0f;
    if (i < 4) accs[i] = 0.0f;
}

__global__ void enc_gate(const float* G, const float* b_f, const float* b_b,
                         const int* len, int t, float* h, float* c) {
    int idx = blockIdx.x * 256 + threadIdx.x;  // 2*B*H
    int dir = idx >> 20;
    int r = idx & ((1 << 20) - 1);
    int b = r >> 10, j = r & (H_ - 1);
    if (t >= len[b]) return;  // masked: keep h, c
    const float* bias = dir ? b_b : b_f;
    const float* g = G + (size_t)(dir * B_ + b) * 4096;
    float gi = g[j] + bias[j];
    float gf = g[H_ + j] + bias[H_ + j];
    float gg = g[2 * H_ + j] + bias[2 * H_ + j];
    float go = g[3 * H_ + j] + bias[3 * H_ + j];
    size_t o = (size_t)dir * B_ * H_ + (size_t)b * H_ + j;
    float nc = sigf(gf) * c[o] + sigf(gi) * tanhf(gg);
    float nh = sigf(go) * tanhf(nc);
    c[o] = nc; h[o] = nh;
}

__global__ void latent_ew(const float* ml, const float* eps, float* z, float* klacc) {
    int idx = blockIdx.x * 256 + threadIdx.x;  // B*L
    int b = idx >> 7, l = idx & (L_ - 1);
    float mean = ml[(size_t)b * 256 + l];
    float logv = ml[(size_t)b * 256 + L_ + l];
    z[idx] = eps[idx] * expf(0.5f * logv) + mean;
    float part = 1.0f + logv - mean * mean - expf(logv);
    for (int off = 32; off; off >>= 1) part += __shfl_down(part, off);
    __shared__ float s[4];
    int lane = threadIdx.x & 63, w = threadIdx.x >> 6;
    if (lane == 0) s[w] = part;
    __syncthreads();
    if (threadIdx.x == 0) atomicAdd(klacc, s[0] + s[1] + s[2] + s[3]);
}

__global__ void dec_gate(const float* G, const float* emb, const int* tokens,
                         const float* z, float* h, float* c, float* ah, int t) {
    int idx = blockIdx.x * 256 + threadIdx.x;  // B*1280
    if (idx >= B_ * (E_ + H_ + L_)) return;
    int b = idx / (E_ + H_ + L_);
    int j = idx - b * (E_ + H_ + L_);
    float* arow = ah + (size_t)b * (E_ + H_ + L_);
    if (j < E_) {
        float xv = 0.0f;
        if (t > 0) { int tok = tokens[(size_t)b * T_ + (t - 1)]; xv = emb[(size_t)tok * E_ + j]; }
        arow[j] = xv;
    } else if (j < E_ + H_) {
        int jj = j - E_;
        const float* g = G + (size_t)b * 4096;
        float gi = sigf(g[jj]);
        float go = sigf(g[H_ + jj]);
        float gf = sigf(g[2 * H_ + jj]);
        float gg = tanhf(g[3 * H_ + jj]);
        size_t o = (size_t)b * H_ + jj;
        float hold = h[o];
        arow[j] = hold;                    // ah uses pre-update h
        float nc = gf * c[o] + gi * gg;
        c[o] = nc;
        h[o] = go * tanhf(nc);
    } else {
        arow[j] = z[(size_t)b * L_ + (j - E_ - H_)];
    }
}

__global__ __launch_bounds__(256) void score_loss(const float* hid1, const float* W2,
                                                  const float* b2, const int* tokens,
                                                  const int* len, int t, float* accs) {
    int b = blockIdx.x;
    if (t > len[b]) return;  // not in mask_dec
    float part[V_];
#pragma unroll
    for (int v = 0; v < V_; ++v) part[v] = 0.0f;
    const float* hrow = hid1 + (size_t)b * H_;
    for (int k = threadIdx.x; k < H_; k += 256) {
        float hv = hrow[k];
#pragma unroll
        for (int v = 0; v < V_; ++v) part[v] += hv * W2[(size_t)v * H_ + k];
    }
    __shared__ float s[V_][4];
    int lane = threadIdx.x & 63, w = threadIdx.x >> 6;
#pragma unroll
    for (int v = 0; v < V_; ++v) {
        float x = part[v];
        for (int off = 32; off; off >>= 1) x += __shfl_down(x, off);
        if (lane == 0) s[v][w] = x;
    }
    __syncthreads();
    if (threadIdx.x == 0) {
        float sc[V_];
        float mx = -1e30f; int am = 0;
        for (int v = 0; v < V_; ++v) {
            sc[v] = s[v][0] + s[v][1] + s[v][2] + s[v][3] + b2[v];
            if (sc[v] > mx) { mx = sc[v]; am = v; }
        }
        float se = 0.0f;
        for (int v = 0; v < V_; ++v) se += expf(sc[v] - mx);
        float lse = mx + logf(se);
        int tgt = (t < len[b]) ? tokens[(size_t)b * T_ + t] : 0;
        atomicAdd(&accs[0], lse - sc[tgt]);
        atomicAdd(&accs[1], (am == tgt) ? 1.0f : 0.0f);
        atomicAdd(&accs[2], 1.0f);
    }
}

__global__ void finalize_k(const float* accs, float* out) {
    if (threadIdx.x == 0 && blockIdx.x == 0) {
        float kl = -0.5f * accs[3] / (float)B_;
        float amino = accs[0] / (float)B_;
        out[0] = amino + 0.1f * kl;
        out[1] = amino;
        out[2] = kl;
        out[3] = accs[1] / accs[2];
    }
}

// ---------------- host ----------------
extern "C" void kernel_launch(void* const* d_in, const int* in_sizes, int n_in,
                              void* d_out, int out_size, void* d_ws, size_t ws_size,
                              hipStream_t stream) {
    (void)in_sizes; (void)n_in; (void)out_size; (void)ws_size;
    const float* x_enc  = (const float*)d_in[0];
    const int*   tokens = (const int*)d_in[1];
    const int*   lengths= (const int*)d_in[2];
    const float* eps    = (const float*)d_in[3];
    const float* emb    = (const float*)d_in[4];
    const float* Wih_f  = (const float*)d_in[5];
    const float* Whh_f  = (const float*)d_in[6];
    const float* b_f    = (const float*)d_in[7];
    const float* Wih_b  = (const float*)d_in[8];
    const float* Whh_b  = (const float*)d_in[9];
    const float* b_b    = (const float*)d_in[10];
    const float* Wm     = (const float*)d_in[11];
    const float* bm     = (const float*)d_in[12];
    const float* Wl     = (const float*)d_in[13];
    const float* bl     = (const float*)d_in[14];
    const float* Wz     = (const float*)d_in[15];
    const float* bz     = (const float*)d_in[16];
    const float* Wi     = (const float*)d_in[17];
    const float* bi     = (const float*)d_in[18];
    const float* Wo     = (const float*)d_in[19];
    const float* bo     = (const float*)d_in[20];
    const float* bWf    = (const float*)d_in[21];
    const float* bf     = (const float*)d_in[22];
    const float* Wg     = (const float*)d_in[23];
    const float* bg     = (const float*)d_in[24];
    const float* W1     = (const float*)d_in[25];
    const float* b1     = (const float*)d_in[26];
    const float* W2     = (const float*)d_in[27];
    const float* b2     = (const float*)d_in[28];

    float* ws   = (float*)d_ws;
    float* henc = ws;                               // 2*B*H
    float* cenc = henc + 2 * B_ * H_;               // 2*B*H
    float* G    = cenc + 2 * B_ * H_;               // 2048*4096
    float* ml   = G + 2048 * 4096;                  // B*256
    float* z    = ml + B_ * 256;                    // B*L
    float* hdec = z + B_ * L_;                      // B*H
    float* cdec = hdec + B_ * H_;                   // B*H
    float* ah   = cdec + B_ * H_;                   // B*1280
    float* hid1 = ah + B_ * (E_ + H_ + L_);         // B*H
    float* accs = hid1 + B_ * H_;                   // [ce, correct, maskcnt, klsum]

    init_zero<<<(2 * B_ * H_) / 256, 256, 0, stream>>>(henc, cenc, cdec, accs);

    // ---- encoder: 15 steps, both directions fused (M = 2048) ----
    for (int t = 0; t < T_; ++t) {
        LdEncA la{x_enc, henc, lengths, t};
        LdEncW lw{Wih_f, Whh_f, Wih_b, Whh_b};
        StPlain st{G, 4096};
        gemm128<<<dim3(32, 16), 256, 0, stream>>>(la, lw, st, E_ + H_);
        enc_gate<<<(2 * B_ * H_) / 256, 256, 0, stream>>>(G, b_f, b_b, lengths, t, henc, cenc);
    }

    // ---- latents: mean/logv GEMM (N=256, K=2048), then z + KL ----
    {
        LdHidA la{henc};
        LdMLW lw{Wm, Wl};
        StML st{ml, bm, bl};
        gemm128<<<dim3(2, 8), 256, 0, stream>>>(la, lw, st, 2 * H_);
    }
    latent_ew<<<(B_ * L_) / 256, 256, 0, stream>>>(ml, eps, z, &accs[3]);

    // ---- h0 = z @ Wz^T + bz ----
    {
        LdRowA la{z, L_};
        LdRowW lw{Wz, L_};
        StBias st{hdec, bz, H_};
        gemm128<<<dim3(8, 8), 256, 0, stream>>>(la, lw, st, L_);
    }

    // ---- decoder: 15 steps ----
    for (int t = 0; t < T_; ++t) {
        {
            LdDecA la{emb, tokens, hdec, t};
            LdDecW lw{Wi, Wo, bWf, Wg};
            StDecG st{G, bi, bo, bf, bg};
            gemm128<<<dim3(32, 8), 256, 0, stream>>>(la, lw, st, E_ + H_);
        }
        dec_gate<<<(B_ * (E_ + H_ + L_) + 255) / 256, 256, 0, stream>>>(
            G, emb, tokens, z, hdec, cdec, ah, t);
        {
            LdRowA la{ah, E_ + H_ + L_};
            LdRowW lw{W1, E_ + H_ + L_};
            StBiasRelu st{hid1, b1, H_};
            gemm128<<<dim3(8, 8), 256, 0, stream>>>(la, lw, st, E_ + H_ + L_);
        }
        score_loss<<<B_, 256, 0, stream>>>(hid1, W2, b2, tokens, lengths, t, accs);
    }

    finalize_k<<<1, 64, 0, stream>>>(accs, (float*)d_out);
}

// Round 2
// 2826.248 us; speedup vs baseline: 5.0991x; 5.0991x over previous
//
#include <hip/hip_runtime.h>
#include <math.h>

#define B_ 1024
#define T_ 15
#define E_ 128
#define H_ 1024
#define L_ 128
#define V_ 21

typedef __attribute__((ext_vector_type(8))) short bf16x8;
typedef __attribute__((ext_vector_type(4))) float f32x4;

__device__ __forceinline__ float sigf(float x) { return 1.0f / (1.0f + expf(-x)); }

// fp32 -> bf16 round-to-nearest-even
__device__ __forceinline__ ushort f2bf(float f) {
    unsigned u = __float_as_uint(f);
    u += 0x7fffu + ((u >> 16) & 1u);
    return (ushort)(u >> 16);
}

__device__ __forceinline__ void gl_lds16(const ushort* g, ushort* l) {
    __builtin_amdgcn_global_load_lds(
        (const __attribute__((address_space(1))) void*)g,
        (__attribute__((address_space(3))) void*)l, 16, 0, 0);
}

// ================= bf16 MFMA GEMM: C = A @ W^T =================
// A: [M][lda] bf16 row-major (K-contiguous). W: [N][ldw] bf16 (K-contiguous),
// per-128-row-block weight base advance wblk (encoder dir select via bm>>10).
// Tile 128x128, BK=32, 256 threads = 4 waves, each wave 64x64 (4x4 frags of 16x16).
// EPI: 0 = plain fp32 store; 1 = +bias fp32; 2 = relu(+bias) fp32; 3 = +bias, bf16 store.
template <int EPI>
__global__ __launch_bounds__(256) void gemm_bf16(
    const ushort* __restrict__ A, int lda,
    const ushort* __restrict__ W, int ldw, long wblk,
    void* __restrict__ Cv, int ldc, const float* __restrict__ bias, int K)
{
    __shared__ ushort As[128 * 32];
    __shared__ ushort Bs[128 * 32];
    const int bn = blockIdx.x * 128;
    const int bm = blockIdx.y * 128;
    const int tid = threadIdx.x;
    const int lane = tid & 63, w = tid >> 6;
    const int wr = w >> 1, wc = w & 1;

    const ushort* Wb = W + (long)(bm >> 10) * wblk;

    // staging: thread tid covers LDS elements [tid*8, tid*8+8) (+2048 for 2nd issue)
    const int srow = tid >> 2;            // 0..63
    const int scol = (tid & 3) * 8;       // 0,8,16,24
    const ushort* agp0 = A + (long)(bm + srow) * lda + scol;
    const ushort* agp1 = A + (long)(bm + 64 + srow) * lda + scol;
    const ushort* wgp0 = Wb + (long)(bn + srow) * ldw + scol;
    const ushort* wgp1 = Wb + (long)(bn + 64 + srow) * ldw + scol;
    ushort* aldsp = As + w * 512;
    ushort* bldsp = Bs + w * 512;

    // fragment read addresses
    const int frow = lane & 15;
    const int fk = (lane >> 4) * 8;
    const ushort* asp = As + (wr * 64 + frow) * 32 + fk;
    const ushort* bsp = Bs + (wc * 64 + frow) * 32 + fk;

    f32x4 acc[4][4];
#pragma unroll
    for (int m = 0; m < 4; ++m)
#pragma unroll
        for (int n = 0; n < 4; ++n) acc[m][n] = (f32x4)0.0f;

    for (int k0 = 0; k0 < K; k0 += 32) {
        gl_lds16(agp0 + k0, aldsp);
        gl_lds16(agp1 + k0, aldsp + 2048);
        gl_lds16(wgp0 + k0, bldsp);
        gl_lds16(wgp1 + k0, bldsp + 2048);
        __syncthreads();
        bf16x8 af[4], bfr[4];
#pragma unroll
        for (int m = 0; m < 4; ++m) af[m] = *(const bf16x8*)(asp + m * 512);
#pragma unroll
        for (int n = 0; n < 4; ++n) bfr[n] = *(const bf16x8*)(bsp + n * 512);
#pragma unroll
        for (int m = 0; m < 4; ++m)
#pragma unroll
            for (int n = 0; n < 4; ++n)
                acc[m][n] = __builtin_amdgcn_mfma_f32_16x16x32_bf16(af[m], bfr[n], acc[m][n], 0, 0, 0);
        __syncthreads();
    }

    // C/D layout: col = lane&15, row = (lane>>4)*4 + reg
#pragma unroll
    for (int m = 0; m < 4; ++m) {
        int row0 = bm + wr * 64 + m * 16 + ((lane >> 4) << 2);
#pragma unroll
        for (int n = 0; n < 4; ++n) {
            int col = bn + wc * 64 + n * 16 + (lane & 15);
            f32x4 v = acc[m][n];
#pragma unroll
            for (int r = 0; r < 4; ++r) {
                float x = v[r];
                if (EPI >= 1) x += bias[col];
                if (EPI == 2) x = fmaxf(x, 0.0f);
                if (EPI == 3)
                    ((ushort*)Cv)[(size_t)(row0 + r) * ldc + col] = f2bf(x);
                else
                    ((float*)Cv)[(size_t)(row0 + r) * ldc + col] = x;
            }
        }
    }
}

// ================= packing / elementwise =================

// copy fp32 [rows][src_ld] -> bf16 dst[r][dcol0 + c] with dst_ld
__global__ void pack_cols(const float* __restrict__ src, int src_ld,
                          ushort* __restrict__ dst, int dst_ld, int dcol0,
                          int rows, int cols) {
    int i = blockIdx.x * 256 + threadIdx.x;
    int c4cnt = cols >> 2;
    if (i >= rows * c4cnt) return;
    int r = i / c4cnt, c4 = (i - r * c4cnt) * 4;
    float4 v = *(const float4*)(src + (size_t)r * src_ld + c4);
    ushort4 o = { f2bf(v.x), f2bf(v.y), f2bf(v.z), f2bf(v.w) };
    *(ushort4*)(dst + (size_t)r * dst_ld + dcol0 + c4) = o;
}

__global__ void init_zero(float* cenc, ushort* Aenc, ushort* ahp, float* accs) {
    int idx = blockIdx.x * 256 + threadIdx.x;   // grid covers 2359296
    if (idx < 2 * B_ * H_) cenc[idx] = 0.0f;
    if (idx < 2048 * 1152) Aenc[idx] = 0;
    if (idx < B_ * E_) ahp[(size_t)(idx >> 7) * 1280 + (idx & 127)] = 0;
    if (idx < 8) accs[idx] = 0.0f;
}

// write x columns of encoder A panel for step t (both directions)
__global__ void pack_encX(const float* __restrict__ xenc, const int* __restrict__ len,
                          int t, ushort* __restrict__ Aenc) {
    int i = blockIdx.x * 256 + threadIdx.x;     // 2048*32
    int r = i >> 5, c4 = (i & 31) * 4;
    int dir = r >> 10, b = r & (B_ - 1);
    int tt = t;
    if (dir) {
        int ri = len[b] - 1 - t;
        tt = ri < 0 ? 0 : (ri > T_ - 1 ? T_ - 1 : ri);
    }
    float4 v = *(const float4*)(xenc + ((size_t)b * T_ + tt) * E_ + c4);
    ushort4 o = { f2bf(v.x), f2bf(v.y), f2bf(v.z), f2bf(v.w) };
    *(ushort4*)(Aenc + (size_t)r * 1152 + c4) = o;
}

// LSTM cell for both encoder directions; writes bf16 h into A panel + hidp
__global__ void enc_gate(const float* __restrict__ G, const float* __restrict__ b_f,
                         const float* __restrict__ b_b, const int* __restrict__ len,
                         int t, float* __restrict__ c, ushort* __restrict__ Aenc,
                         ushort* __restrict__ hidp) {
    int idx = blockIdx.x * 256 + threadIdx.x;   // 2*B*H
    int dir = idx >> 20, r = idx & ((1 << 20) - 1);
    int b = r >> 10, j = r & (H_ - 1);
    if (t >= len[b]) return;                    // masked: keep h, c
    const float* bias = dir ? b_b : b_f;
    const float* g = G + (size_t)(dir * B_ + b) * 4096;
    float gi = g[j] + bias[j];
    float gf = g[H_ + j] + bias[H_ + j];
    float gg = g[2 * H_ + j] + bias[2 * H_ + j];
    float go = g[3 * H_ + j] + bias[3 * H_ + j];
    float nc = sigf(gf) * c[idx] + sigf(gi) * tanhf(gg);
    float nh = sigf(go) * tanhf(nc);
    c[idx] = nc;
    ushort hb = f2bf(nh);
    Aenc[(size_t)(dir * B_ + b) * 1152 + 128 + j] = hb;
    hidp[(size_t)b * 2048 + dir * H_ + j] = hb;
}

// z = eps*exp(0.5*logv)+mean (bf16 to zp and ah z-cols), KL partial sum
__global__ void latent_ew(const float* __restrict__ ml, const float* __restrict__ bm,
                          const float* __restrict__ bl, const float* __restrict__ eps,
                          ushort* __restrict__ zp, ushort* __restrict__ ahp,
                          float* __restrict__ klacc) {
    int idx = blockIdx.x * 256 + threadIdx.x;   // B*L
    int b = idx >> 7, l = idx & (L_ - 1);
    float mean = ml[(size_t)b * 256 + l] + bm[l];
    float logv = ml[(size_t)b * 256 + L_ + l] + bl[l];
    float zv = eps[idx] * expf(0.5f * logv) + mean;
    ushort zb = f2bf(zv);
    zp[idx] = zb;
    ahp[(size_t)b * 1280 + 1152 + l] = zb;
    float part = 1.0f + logv - mean * mean - expf(logv);
    for (int off = 32; off; off >>= 1) part += __shfl_down(part, off);
    __shared__ float s[4];
    int lane = threadIdx.x & 63, wv = threadIdx.x >> 6;
    if (lane == 0) s[wv] = part;
    __syncthreads();
    if (threadIdx.x == 0) atomicAdd(klacc, s[0] + s[1] + s[2] + s[3]);
}

// decoder x columns for step t (t>=1; t=0 is zeros from init)
__global__ void pack_ahX(const float* __restrict__ emb, const int* __restrict__ tokens,
                         int t, ushort* __restrict__ ahp) {
    int i = blockIdx.x * 256 + threadIdx.x;     // 1024*32
    int b = i >> 5, c4 = (i & 31) * 4;
    int tok = tokens[(size_t)b * T_ + (t - 1)];
    float4 v = *(const float4*)(emb + (size_t)tok * E_ + c4);
    ushort4 o = { f2bf(v.x), f2bf(v.y), f2bf(v.z), f2bf(v.w) };
    *(ushort4*)(ahp + (size_t)b * 1280 + c4) = o;
}

// decoder LSTM cell: updates c, writes bf16 h into ah h-cols
__global__ void dec_gate(const float* __restrict__ G, const float* __restrict__ bi,
                         const float* __restrict__ bo, const float* __restrict__ bfv,
                         const float* __restrict__ bg, float* __restrict__ c,
                         ushort* __restrict__ ahp, int t) {
    int idx = blockIdx.x * 256 + threadIdx.x;   // B*H
    int b = idx >> 10, j = idx & (H_ - 1);
    const float* g = G + (size_t)b * 4096;
    float gi = sigf(g[j] + bi[j]);
    float go = sigf(g[H_ + j] + bo[j]);
    float gf = sigf(g[2 * H_ + j] + bfv[j]);
    float gg = tanhf(g[3 * H_ + j] + bg[j]);
    float cold = (t == 0) ? 0.0f : c[idx];
    float nc = gf * cold + gi * gg;
    c[idx] = nc;
    ahp[(size_t)b * 1280 + 128 + j] = f2bf(go * tanhf(nc));
}

__global__ __launch_bounds__(256) void score_loss(const float* __restrict__ hid1,
                                                  const float* __restrict__ W2,
                                                  const float* __restrict__ b2,
                                                  const int* __restrict__ tokens,
                                                  const int* __restrict__ len, int t,
                                                  float* __restrict__ accs) {
    int b = blockIdx.x;
    if (t > len[b]) return;  // not in mask_dec
    float part[V_];
#pragma unroll
    for (int v = 0; v < V_; ++v) part[v] = 0.0f;
    const float* hrow = hid1 + (size_t)b * H_;
    for (int k = threadIdx.x; k < H_; k += 256) {
        float hv = hrow[k];
#pragma unroll
        for (int v = 0; v < V_; ++v) part[v] += hv * W2[(size_t)v * H_ + k];
    }
    __shared__ float s[V_][4];
    int lane = threadIdx.x & 63, w = threadIdx.x >> 6;
#pragma unroll
    for (int v = 0; v < V_; ++v) {
        float x = part[v];
        for (int off = 32; off; off >>= 1) x += __shfl_down(x, off);
        if (lane == 0) s[v][w] = x;
    }
    __syncthreads();
    if (threadIdx.x == 0) {
        float sc[V_];
        float mx = -1e30f; int am = 0;
        for (int v = 0; v < V_; ++v) {
            sc[v] = s[v][0] + s[v][1] + s[v][2] + s[v][3] + b2[v];
            if (sc[v] > mx) { mx = sc[v]; am = v; }
        }
        float se = 0.0f;
        for (int v = 0; v < V_; ++v) se += expf(sc[v] - mx);
        float lse = mx + logf(se);
        int tgt = (t < len[b]) ? tokens[(size_t)b * T_ + t] : 0;
        atomicAdd(&accs[0], lse - sc[tgt]);
        atomicAdd(&accs[1], (am == tgt) ? 1.0f : 0.0f);
        atomicAdd(&accs[2], 1.0f);
    }
}

__global__ void finalize_k(const float* accs, float* out) {
    if (threadIdx.x == 0 && blockIdx.x == 0) {
        float kl = -0.5f * accs[3] / (float)B_;
        float amino = accs[0] / (float)B_;
        out[0] = amino + 0.1f * kl;
        out[1] = amino;
        out[2] = kl;
        out[3] = accs[1] / accs[2];
    }
}

// ================= host =================
extern "C" void kernel_launch(void* const* d_in, const int* in_sizes, int n_in,
                              void* d_out, int out_size, void* d_ws, size_t ws_size,
                              hipStream_t stream) {
    (void)in_sizes; (void)n_in; (void)out_size; (void)ws_size;
    const float* x_enc  = (const float*)d_in[0];
    const int*   tokens = (const int*)d_in[1];
    const int*   lengths= (const int*)d_in[2];
    const float* eps    = (const float*)d_in[3];
    const float* emb    = (const float*)d_in[4];
    const float* Wih_f  = (const float*)d_in[5];
    const float* Whh_f  = (const float*)d_in[6];
    const float* b_f    = (const float*)d_in[7];
    const float* Wih_b  = (const float*)d_in[8];
    const float* Whh_b  = (const float*)d_in[9];
    const float* b_b    = (const float*)d_in[10];
    const float* Wm     = (const float*)d_in[11];
    const float* bm     = (const float*)d_in[12];
    const float* Wl     = (const float*)d_in[13];
    const float* bl     = (const float*)d_in[14];
    const float* Wz     = (const float*)d_in[15];
    const float* bz     = (const float*)d_in[16];
    const float* Wi     = (const float*)d_in[17];
    const float* bi     = (const float*)d_in[18];
    const float* Wo     = (const float*)d_in[19];
    const float* bo     = (const float*)d_in[20];
    const float* Wfm    = (const float*)d_in[21];
    const float* bf     = (const float*)d_in[22];
    const float* Wg     = (const float*)d_in[23];
    const float* bg     = (const float*)d_in[24];
    const float* W1     = (const float*)d_in[25];
    const float* b1     = (const float*)d_in[26];
    const float* W2     = (const float*)d_in[27];
    const float* b2     = (const float*)d_in[28];

    // ---- workspace layout (≈87 MiB) ----
    float* cenc = (float*)d_ws;                  // 2*B*H
    float* G    = cenc + 2 * B_ * H_;            // 2048*4096 (enc), decoder uses first 1024*4096
    float* hid1 = G + 4 * 1024 * 1024;           // alias: upper half of G (decoder only)
    float* ml   = G + 8 * 1024 * 1024;           // 1024*256
    float* accs = ml + B_ * 256;                 // 8
    ushort* Wenc = (ushort*)(accs + 8);          // 2*4096*1152
    ushort* Wdec = Wenc + 2 * 4096 * 1152;       // 4096*1152
    ushort* W1p  = Wdec + 4096 * 1152;           // 1024*1280
    ushort* Wml  = W1p + 1024 * 1280;            // 256*2048
    ushort* Wzp  = Wml + 256 * 2048;             // 1024*128
    ushort* Aenc = Wzp + 1024 * 128;             // 2048*1152
    ushort* ahp  = Aenc + 2048 * 1152;           // 1024*1280
    ushort* hidp = ahp + 1024 * 1280;            // 1024*2048
    ushort* zp   = hidp + 1024 * 2048;           // 1024*128
    float* cdec  = (float*)(zp + 1024 * 128);    // B*H

    init_zero<<<9216, 256, 0, stream>>>(cenc, Aenc, ahp, accs);

    // ---- pack weights to bf16 (once per call) ----
    pack_cols<<<512, 256, 0, stream>>>(Wih_f, E_, Wenc, 1152, 0, 4096, E_);
    pack_cols<<<4096, 256, 0, stream>>>(Whh_f, H_, Wenc, 1152, E_, 4096, H_);
    pack_cols<<<512, 256, 0, stream>>>(Wih_b, E_, Wenc + 4096 * 1152, 1152, 0, 4096, E_);
    pack_cols<<<4096, 256, 0, stream>>>(Whh_b, H_, Wenc + 4096 * 1152, 1152, E_, 4096, H_);
    pack_cols<<<1152, 256, 0, stream>>>(Wi,  1152, Wdec + 0 * 1024 * 1152, 1152, 0, 1024, 1152);
    pack_cols<<<1152, 256, 0, stream>>>(Wo,  1152, Wdec + 1 * 1024 * 1152, 1152, 0, 1024, 1152);
    pack_cols<<<1152, 256, 0, stream>>>(Wfm, 1152, Wdec + 2 * 1024 * 1152, 1152, 0, 1024, 1152);
    pack_cols<<<1152, 256, 0, stream>>>(Wg,  1152, Wdec + 3 * 1024 * 1152, 1152, 0, 1024, 1152);
    pack_cols<<<1280, 256, 0, stream>>>(W1, 1280, W1p, 1280, 0, 1024, 1280);
    pack_cols<<<256, 256, 0, stream>>>(Wm, 2048, Wml, 2048, 0, L_, 2048);
    pack_cols<<<256, 256, 0, stream>>>(Wl, 2048, Wml + L_ * 2048, 2048, 0, L_, 2048);
    pack_cols<<<128, 256, 0, stream>>>(Wz, L_, Wzp, L_, 0, H_, L_);

    // ---- encoder: 15 steps, both directions fused (M = 2048) ----
    for (int t = 0; t < T_; ++t) {
        pack_encX<<<256, 256, 0, stream>>>(x_enc, lengths, t, Aenc);
        gemm_bf16<0><<<dim3(32, 16), 256, 0, stream>>>(
            Aenc, 1152, Wenc, 1152, (long)4096 * 1152, G, 4096, nullptr, 1152);
        enc_gate<<<8192, 256, 0, stream>>>(G, b_f, b_b, lengths, t, cenc, Aenc, hidp);
    }

    // ---- latents: [mean|logv] GEMM (M=1024, N=256, K=2048), z + KL ----
    gemm_bf16<0><<<dim3(2, 8), 256, 0, stream>>>(
        hidp, 2048, Wml, 2048, 0, ml, 256, nullptr, 2048);
    latent_ew<<<512, 256, 0, stream>>>(ml, bm, bl, eps, zp, ahp, &accs[3]);

    // ---- h0 = z @ Wz^T + bz  (bf16, straight into ah h-cols) ----
    gemm_bf16<3><<<dim3(8, 8), 256, 0, stream>>>(
        zp, L_, Wzp, L_, 0, ahp + 128, 1280, bz, L_);

    // ---- decoder: 15 steps ----
    for (int t = 0; t < T_; ++t) {
        if (t > 0) pack_ahX<<<128, 256, 0, stream>>>(emb, tokens, t, ahp);
        gemm_bf16<0><<<dim3(32, 8), 256, 0, stream>>>(
            ahp, 1280, Wdec, 1152, 0, G, 4096, nullptr, 1152);
        gemm_bf16<2><<<dim3(8, 8), 256, 0, stream>>>(
            ahp, 1280, W1p, 1280, 0, hid1, 1024, b1, 1280);
        dec_gate<<<4096, 256, 0, stream>>>(G, bi, bo, bf, bg, cdec, ahp, t);
        score_loss<<<B_, 256, 0, stream>>>(hid1, W2, b2, tokens, lengths, t, accs);
    }

    finalize_k<<<1, 64, 0, stream>>>(accs, (float*)d_out);
}

// Round 3
// 1871.776 us; speedup vs baseline: 7.6992x; 1.5099x over previous
//
#include <hip/hip_runtime.h>
#include <math.h>

#define B_ 1024
#define T_ 15
#define E_ 128
#define H_ 1024
#define L_ 128
#define V_ 21

typedef __attribute__((ext_vector_type(8))) short bf16x8;
typedef __attribute__((ext_vector_type(4))) float f32x4;

__device__ __forceinline__ float sigf(float x) { return 1.0f / (1.0f + expf(-x)); }

__device__ __forceinline__ ushort f2bf(float f) {
    unsigned u = __float_as_uint(f);
    u += 0x7fffu + ((u >> 16) & 1u);
    return (ushort)(u >> 16);
}

__device__ __forceinline__ void gl_lds16(const ushort* g, ushort* l) {
    __builtin_amdgcn_global_load_lds(
        (const __attribute__((address_space(1))) void*)g,
        (__attribute__((address_space(3))) void*)l, 16, 0, 0);
}

// ================= double-buffered bf16 MFMA GEMM core =================
// Tile 128x128, BK=32, 4 waves (2x2), each wave 64x64 = 4x4 frags of 16x16x32.
// A via al.addr(row,k) (16B-aligned, 8-elem chunks never straddle regions),
// W via wl.addr(bm,n,k). Epilogue functor consumes acc[4][4].
template <class ALd, class WLd, class Epi>
__global__ __launch_bounds__(256) void gemm_dbuf(ALd al, WLd wl, Epi ep) {
    __shared__ ushort As[2 * 4096];
    __shared__ ushort Ws[2 * 4096];
    const int tid = threadIdx.x;
    const int lane = tid & 63;
    const int w = tid >> 6;
    const int wr = w >> 1, wc = w & 1;
    const int bn = blockIdx.x * 128, bm = blockIdx.y * 128;
    const int srow = tid >> 2, scol = (tid & 3) * 8;
    const int frow = lane & 15, fk = (lane >> 4) * 8;
    const int K = al.kdim(bn);

    ushort* adst = As + w * 512;
    ushort* wdst = Ws + w * 512;

    f32x4 acc[4][4];
#pragma unroll
    for (int m = 0; m < 4; ++m)
#pragma unroll
        for (int n = 0; n < 4; ++n) acc[m][n] = (f32x4)0.0f;

    gl_lds16(al.addr(bm + srow, scol), adst);
    gl_lds16(al.addr(bm + 64 + srow, scol), adst + 2048);
    gl_lds16(wl.addr(bm, bn + srow, scol), wdst);
    gl_lds16(wl.addr(bm, bn + 64 + srow, scol), wdst + 2048);
    __syncthreads();

    const int nk = K >> 5;
    for (int t = 0; t < nk; ++t) {
        const int cb = (t & 1) * 4096;
        const ushort* asp = As + cb + (wr * 64 + frow) * 32 + fk;
        const ushort* bsp = Ws + cb + (wc * 64 + frow) * 32 + fk;
        bf16x8 af[4], bw[4];
#pragma unroll
        for (int m = 0; m < 4; ++m) af[m] = *(const bf16x8*)(asp + m * 512);
#pragma unroll
        for (int n = 0; n < 4; ++n) bw[n] = *(const bf16x8*)(bsp + n * 512);
        if (t + 1 < nk) {   // prefetch next K-tile into the other buffer
            const int k0 = (t + 1) * 32;
            const int nb = ((t + 1) & 1) * 4096;
            gl_lds16(al.addr(bm + srow, k0 + scol), As + nb + w * 512);
            gl_lds16(al.addr(bm + 64 + srow, k0 + scol), As + nb + 2048 + w * 512);
            gl_lds16(wl.addr(bm, bn + srow, k0 + scol), Ws + nb + w * 512);
            gl_lds16(wl.addr(bm, bn + 64 + srow, k0 + scol), Ws + nb + 2048 + w * 512);
        }
#pragma unroll
        for (int m = 0; m < 4; ++m)
#pragma unroll
            for (int n = 0; n < 4; ++n)
                acc[m][n] = __builtin_amdgcn_mfma_f32_16x16x32_bf16(af[m], bw[n], acc[m][n], 0, 0, 0);
        __syncthreads();   // drains vmcnt (next buf ready) + lgkm; full barrier
    }
    ep(bm, bn, wr, wc, lane, acc);
}

// ================= loaders =================
// Gate-interleaved weight row p: j = (p>>6)*16 + (p&15), gate = (p>>4)&3.
// => in the epilogue, acc[m][n] holds gate n for j = ((bn>>6)+wc)*16 + (lane&15).

struct ALdEnc {  // rows: dir*1024+b ; cols: [x_t(128) | h(1024)]
    const ushort* xe;   // [2048][128] for this t
    const ushort* h;    // [2048][1024]
    __device__ int kdim(int) const { return 1152; }
    __device__ const ushort* addr(int row, int k) const {
        return (k < 128) ? xe + (size_t)row * 128 + k
                         : h + (size_t)row * 1024 + (k - 128);
    }
};
struct WLdEnc {
    const ushort* W;    // [2][4096][1152] gate-interleaved
    __device__ const ushort* addr(int bm, int n, int k) const {
        return W + ((size_t)(bm >> 10) * 4096 + n) * 1152 + k;
    }
};
struct ALdDec {  // rows: b ; cols: [x_t(128) | h(1024) | z(128)]
    const ushort* xd;   // [1024][128] for this t
    const ushort* h;    // [1024][1024]
    const ushort* z;    // [1024][128]
    __device__ int kdim(int bn) const { return bn < 4096 ? 1152 : 1280; }
    __device__ const ushort* addr(int row, int k) const {
        if (k < 128) return xd + (size_t)row * 128 + k;
        if (k < 1152) return h + (size_t)row * 1024 + (k - 128);
        return z + (size_t)row * 128 + (k - 1152);
    }
};
struct WLdDec {
    const ushort* Wg4;  // [4096][1152] gate-interleaved (i,o,f,g)
    const ushort* W1;   // [1024][1280]
    __device__ const ushort* addr(int, int n, int k) const {
        return (n < 4096) ? Wg4 + (size_t)n * 1152 + k
                          : W1 + (size_t)(n - 4096) * 1280 + k;
    }
};
struct ALdHid {  // hidden = [h_f | h_b] composed from final h buffer rows
    const ushort* hF;   // [2048][1024]
    __device__ int kdim(int) const { return 2048; }
    __device__ const ushort* addr(int row, int k) const {
        return hF + ((size_t)((k >> 10) << 10) + row) * 1024 + (k & 1023);
    }
};
struct ALdPlain {
    const ushort* A; int ld; int K;
    __device__ int kdim(int) const { return K; }
    __device__ const ushort* addr(int row, int k) const { return A + (size_t)row * ld + k; }
};
struct WLdPlain {
    const ushort* W; int ld;
    __device__ const ushort* addr(int, int n, int k) const { return W + (size_t)n * ld + k; }
};

// ================= epilogues =================
struct EpiEnc {  // fused encoder LSTM cell, gates order (i,f,g,o) = frags 0..3
    const float* b_f; const float* b_b; const int* len; int t;
    float* c;               // [2048][1024]
    const ushort* hc;       // h_cur [2048][1024]
    ushort* hn;             // h_next [2048][1024]
    __device__ void operator()(int bm, int bn, int wr, int wc, int lane,
                               f32x4 (&acc)[4][4]) const {
        const int j = ((bn >> 6) + wc) * 16 + (lane & 15);
        const int rbase = bm + wr * 64 + ((lane >> 4) << 2);
#pragma unroll
        for (int m = 0; m < 4; ++m) {
#pragma unroll
            for (int r = 0; r < 4; ++r) {
                const int row = rbase + m * 16 + r;
                const int b = row & 1023;
                const float* bias = (row >> 10) ? b_b : b_f;
                const size_t o = (size_t)row * 1024 + j;
                if (t < len[b]) {
                    float gi = acc[m][0][r] + bias[j];
                    float gf = acc[m][1][r] + bias[1024 + j];
                    float gg = acc[m][2][r] + bias[2048 + j];
                    float go = acc[m][3][r] + bias[3072 + j];
                    float nc = sigf(gf) * c[o] + sigf(gi) * tanhf(gg);
                    c[o] = nc;
                    hn[o] = f2bf(sigf(go) * tanhf(nc));
                } else {
                    hn[o] = hc[o];
                }
            }
        }
    }
};
struct EpiDec {  // gates blocks: fused cell (i,o,f,g); W1 blocks: relu+bias
    const float *bi, *bo, *bfv, *bg, *b1;
    float* c;               // [1024][1024]
    ushort* hn;             // h_next [1024][1024]
    float* hid1;            // [1024][1024]
    __device__ void operator()(int bm, int bn, int wr, int wc, int lane,
                               f32x4 (&acc)[4][4]) const {
        const int rbase = bm + wr * 64 + ((lane >> 4) << 2);
        if (bn < 4096) {
            const int j = ((bn >> 6) + wc) * 16 + (lane & 15);
#pragma unroll
            for (int m = 0; m < 4; ++m) {
#pragma unroll
                for (int r = 0; r < 4; ++r) {
                    const int b = rbase + m * 16 + r;
                    const size_t o = (size_t)b * 1024 + j;
                    float gi = sigf(acc[m][0][r] + bi[j]);
                    float go = sigf(acc[m][1][r] + bo[j]);
                    float gf = sigf(acc[m][2][r] + bfv[j]);
                    float gg = tanhf(acc[m][3][r] + bg[j]);
                    float nc = gf * c[o] + gi * gg;
                    c[o] = nc;
                    hn[o] = f2bf(go * tanhf(nc));
                }
            }
        } else {
            const int cb = (bn - 4096) + wc * 64;
#pragma unroll
            for (int m = 0; m < 4; ++m) {
#pragma unroll
                for (int n = 0; n < 4; ++n) {
                    const int col = cb + n * 16 + (lane & 15);
#pragma unroll
                    for (int r = 0; r < 4; ++r) {
                        float x = fmaxf(acc[m][n][r] + b1[col], 0.0f);
                        hid1[(size_t)(rbase + m * 16 + r) * 1024 + col] = x;
                    }
                }
            }
        }
    }
};
struct EpiStoreF32 {
    float* out; int ldc;
    __device__ void operator()(int bm, int bn, int wr, int wc, int lane,
                               f32x4 (&acc)[4][4]) const {
        const int rbase = bm + wr * 64 + ((lane >> 4) << 2);
        const int cbase = bn + wc * 64 + (lane & 15);
#pragma unroll
        for (int m = 0; m < 4; ++m)
#pragma unroll
            for (int n = 0; n < 4; ++n)
#pragma unroll
                for (int r = 0; r < 4; ++r)
                    out[(size_t)(rbase + m * 16 + r) * ldc + cbase + n * 16] = acc[m][n][r];
    }
};
struct EpiBiasBf16 {  // for h0 = z@Wz^T + bz
    ushort* out; const float* bias;
    __device__ void operator()(int bm, int bn, int wr, int wc, int lane,
                               f32x4 (&acc)[4][4]) const {
        const int rbase = bm + wr * 64 + ((lane >> 4) << 2);
        const int cbase = bn + wc * 64 + (lane & 15);
#pragma unroll
        for (int m = 0; m < 4; ++m)
#pragma unroll
            for (int n = 0; n < 4; ++n) {
                const int col = cbase + n * 16;
#pragma unroll
                for (int r = 0; r < 4; ++r)
                    out[(size_t)(rbase + m * 16 + r) * 1024 + col] = f2bf(acc[m][n][r] + bias[col]);
            }
    }
};

// ================= packing / elementwise =================
__global__ void pack_cols(const float* __restrict__ src, int src_ld,
                          ushort* __restrict__ dst, int dst_ld, int dcol0,
                          int rows, int cols) {
    int i = blockIdx.x * 256 + threadIdx.x;
    int c4cnt = cols >> 2;
    if (i >= rows * c4cnt) return;
    int r = i / c4cnt, c4 = (i - r * c4cnt) * 4;
    float4 v = *(const float4*)(src + (size_t)r * src_ld + c4);
    ushort4 o = { f2bf(v.x), f2bf(v.y), f2bf(v.z), f2bf(v.w) };
    *(ushort4*)(dst + (size_t)r * dst_ld + dcol0 + c4) = o;
}

// encoder weights: [2][4096][1152], row p <- stacked gate row (p>>4)&3, j=(p>>6)*16+(p&15)
__global__ void pack_gates_enc(const float* __restrict__ Wih_f, const float* __restrict__ Whh_f,
                               const float* __restrict__ Wih_b, const float* __restrict__ Whh_b,
                               ushort* __restrict__ dst) {
    int i = blockIdx.x * 256 + threadIdx.x;   // 2*4096*288
    if (i >= 2 * 4096 * 288) return;
    int c4 = (i % 288) * 4;
    int p = (i / 288) & 4095;
    int dir = i / (288 * 4096);
    int j = ((p >> 6) << 4) + (p & 15);
    int g = (p >> 4) & 3;
    int srow = g * 1024 + j;
    float4 v;
    if (c4 < 128) {
        const float* s = dir ? Wih_b : Wih_f;
        v = *(const float4*)(s + (size_t)srow * 128 + c4);
    } else {
        const float* s = dir ? Whh_b : Whh_f;
        v = *(const float4*)(s + (size_t)srow * 1024 + (c4 - 128));
    }
    ushort4 o = { f2bf(v.x), f2bf(v.y), f2bf(v.z), f2bf(v.w) };
    *(ushort4*)(dst + ((size_t)dir * 4096 + p) * 1152 + c4) = o;
}

// decoder gate weights: [4096][1152], frag order 0:Wi 1:Wo 2:Wf 3:Wg
__global__ void pack_gates_dec(const float* __restrict__ Wi, const float* __restrict__ Wo,
                               const float* __restrict__ Wf, const float* __restrict__ Wg,
                               ushort* __restrict__ dst) {
    int i = blockIdx.x * 256 + threadIdx.x;   // 4096*288
    if (i >= 4096 * 288) return;
    int c4 = (i % 288) * 4;
    int p = i / 288;
    int j = ((p >> 6) << 4) + (p & 15);
    int g = (p >> 4) & 3;
    const float* s = (g == 0) ? Wi : (g == 1) ? Wo : (g == 2) ? Wf : Wg;
    float4 v = *(const float4*)(s + (size_t)j * 1152 + c4);
    ushort4 o = { f2bf(v.x), f2bf(v.y), f2bf(v.z), f2bf(v.w) };
    *(ushort4*)(dst + (size_t)p * 1152 + c4) = o;
}

// all encoder x panels (both dirs, with bwd length-reversal): xe[t][2048][128]
__global__ void pack_xenc(const float* __restrict__ xenc, const int* __restrict__ len,
                          ushort* __restrict__ xe) {
    int i = blockIdx.x * 256 + threadIdx.x;   // 15*2048*32
    if (i >= 15 * 2048 * 32) return;
    int c4 = (i & 31) * 4;
    int r = (i >> 5) & 2047;
    int t = i >> 16;
    int dir = r >> 10, b = r & 1023;
    int tt = t;
    if (dir) {
        int ri = len[b] - 1 - t;
        tt = ri < 0 ? 0 : (ri > T_ - 1 ? T_ - 1 : ri);
    }
    float4 v = *(const float4*)(xenc + ((size_t)b * T_ + tt) * 128 + c4);
    ushort4 o = { f2bf(v.x), f2bf(v.y), f2bf(v.z), f2bf(v.w) };
    *(ushort4*)(xe + ((size_t)t * 2048 + r) * 128 + c4) = o;
}

// all decoder x panels: xd[t][1024][128]; t=0 zeros, else emb[tokens[:,t-1]]
__global__ void pack_xdec(const float* __restrict__ emb, const int* __restrict__ tokens,
                          ushort* __restrict__ xd) {
    int i = blockIdx.x * 256 + threadIdx.x;   // 15*1024*32
    if (i >= 15 * 1024 * 32) return;
    int c4 = (i & 31) * 4;
    int b = (i >> 5) & 1023;
    int t = i >> 15;
    ushort4 o = { 0, 0, 0, 0 };
    if (t > 0) {
        int tok = tokens[(size_t)b * T_ + (t - 1)];
        float4 v = *(const float4*)(emb + (size_t)tok * 128 + c4);
        o = ushort4{ f2bf(v.x), f2bf(v.y), f2bf(v.z), f2bf(v.w) };
    }
    *(ushort4*)(xd + ((size_t)t * 1024 + b) * 128 + c4) = o;
}

__global__ void init_zero(float* cenc, float* cdec, ushort* hA, float* accs) {
    int i = blockIdx.x * 256 + threadIdx.x;   // 2M
    if (i < 2 * 1024 * 1024) { cenc[i] = 0.0f; hA[i] = 0; }
    if (i < 1024 * 1024) cdec[i] = 0.0f;
    if (i < 8) accs[i] = 0.0f;
}

__global__ void latent_ew(const float* __restrict__ ml, const float* __restrict__ bmv,
                          const float* __restrict__ blv, const float* __restrict__ eps,
                          ushort* __restrict__ zp, float* __restrict__ klacc) {
    int idx = blockIdx.x * 256 + threadIdx.x;   // B*L
    int b = idx >> 7, l = idx & (L_ - 1);
    float mean = ml[(size_t)b * 256 + l] + bmv[l];
    float logv = ml[(size_t)b * 256 + L_ + l] + blv[l];
    zp[idx] = f2bf(eps[idx] * expf(0.5f * logv) + mean);
    float part = 1.0f + logv - mean * mean - expf(logv);
    for (int off = 32; off; off >>= 1) part += __shfl_down(part, off);
    __shared__ float s[4];
    int lane = threadIdx.x & 63, wv = threadIdx.x >> 6;
    if (lane == 0) s[wv] = part;
    __syncthreads();
    if (threadIdx.x == 0) atomicAdd(klacc, s[0] + s[1] + s[2] + s[3]);
}

__global__ __launch_bounds__(256) void score_loss(const float* __restrict__ hid1,
                                                  const float* __restrict__ W2,
                                                  const float* __restrict__ b2,
                                                  const int* __restrict__ tokens,
                                                  const int* __restrict__ len, int t,
                                                  float* __restrict__ accs) {
    int b = blockIdx.x;
    if (t > len[b]) return;
    float part[V_];
#pragma unroll
    for (int v = 0; v < V_; ++v) part[v] = 0.0f;
    const float* hrow = hid1 + (size_t)b * H_;
    for (int k = threadIdx.x; k < H_; k += 256) {
        float hv = hrow[k];
#pragma unroll
        for (int v = 0; v < V_; ++v) part[v] += hv * W2[(size_t)v * H_ + k];
    }
    __shared__ float s[V_][4];
    int lane = threadIdx.x & 63, w = threadIdx.x >> 6;
#pragma unroll
    for (int v = 0; v < V_; ++v) {
        float x = part[v];
        for (int off = 32; off; off >>= 1) x += __shfl_down(x, off);
        if (lane == 0) s[v][w] = x;
    }
    __syncthreads();
    if (threadIdx.x == 0) {
        float sc[V_];
        float mx = -1e30f; int am = 0;
        for (int v = 0; v < V_; ++v) {
            sc[v] = s[v][0] + s[v][1] + s[v][2] + s[v][3] + b2[v];
            if (sc[v] > mx) { mx = sc[v]; am = v; }
        }
        float se = 0.0f;
        for (int v = 0; v < V_; ++v) se += expf(sc[v] - mx);
        float lse = mx + logf(se);
        int tgt = (t < len[b]) ? tokens[(size_t)b * T_ + t] : 0;
        atomicAdd(&accs[0], lse - sc[tgt]);
        atomicAdd(&accs[1], (am == tgt) ? 1.0f : 0.0f);
        atomicAdd(&accs[2], 1.0f);
    }
}

__global__ void finalize_k(const float* accs, float* out) {
    if (threadIdx.x == 0 && blockIdx.x == 0) {
        float kl = -0.5f * accs[3] / (float)B_;
        float amino = accs[0] / (float)B_;
        out[0] = amino + 0.1f * kl;
        out[1] = amino;
        out[2] = kl;
        out[3] = accs[1] / accs[2];
    }
}

// ================= host =================
extern "C" void kernel_launch(void* const* d_in, const int* in_sizes, int n_in,
                              void* d_out, int out_size, void* d_ws, size_t ws_size,
                              hipStream_t stream) {
    (void)in_sizes; (void)n_in; (void)out_size; (void)ws_size;
    const float* x_enc  = (const float*)d_in[0];
    const int*   tokens = (const int*)d_in[1];
    const int*   lengths= (const int*)d_in[2];
    const float* eps    = (const float*)d_in[3];
    const float* emb    = (const float*)d_in[4];
    const float* Wih_f  = (const float*)d_in[5];
    const float* Whh_f  = (const float*)d_in[6];
    const float* b_f    = (const float*)d_in[7];
    const float* Wih_b  = (const float*)d_in[8];
    const float* Whh_b  = (const float*)d_in[9];
    const float* b_b    = (const float*)d_in[10];
    const float* Wm     = (const float*)d_in[11];
    const float* bm     = (const float*)d_in[12];
    const float* Wl     = (const float*)d_in[13];
    const float* bl     = (const float*)d_in[14];
    const float* Wz     = (const float*)d_in[15];
    const float* bz     = (const float*)d_in[16];
    const float* Wi     = (const float*)d_in[17];
    const float* bi     = (const float*)d_in[18];
    const float* Wo     = (const float*)d_in[19];
    const float* bo     = (const float*)d_in[20];
    const float* Wfm    = (const float*)d_in[21];
    const float* bf     = (const float*)d_in[22];
    const float* Wg     = (const float*)d_in[23];
    const float* bg     = (const float*)d_in[24];
    const float* W1     = (const float*)d_in[25];
    const float* b1     = (const float*)d_in[26];
    const float* W2     = (const float*)d_in[27];
    const float* b2     = (const float*)d_in[28];

    // ---- workspace (~73 MiB) ----
    float*  cenc = (float*)d_ws;                    // 2M f32
    float*  cdec = cenc + 2 * 1024 * 1024;          // 1M f32
    float*  ml   = cdec + 1024 * 1024;              // 1024*256 f32
    float*  hid1 = ml + 1024 * 256;                 // 1M f32
    float*  accs = hid1 + 1024 * 1024;              // 8 (+pad)
    ushort* hA   = (ushort*)(accs + 64);            // 2M
    ushort* hB   = hA + 2 * 1024 * 1024;            // 2M
    ushort* hdA  = hB + 2 * 1024 * 1024;            // 1M
    ushort* hdB  = hdA + 1024 * 1024;               // 1M
    ushort* zp   = hdB + 1024 * 1024;               // 128K
    ushort* xe   = zp + 1024 * 128;                 // 15*2048*128
    ushort* xd   = xe + 15 * 2048 * 128;            // 15*1024*128
    ushort* Wenc = xd + 15 * 1024 * 128;            // 2*4096*1152
    ushort* Wdec = Wenc + 2 * 4096 * 1152;          // 4096*1152
    ushort* W1p  = Wdec + 4096 * 1152;              // 1024*1280
    ushort* Wml  = W1p + 1024 * 1280;               // 256*2048
    ushort* Wzp  = Wml + 256 * 2048;                // 1024*128

    // ---- prep (9 launches) ----
    init_zero<<<8192, 256, 0, stream>>>(cenc, cdec, hA, accs);
    pack_gates_enc<<<9216, 256, 0, stream>>>(Wih_f, Whh_f, Wih_b, Whh_b, Wenc);
    pack_gates_dec<<<4608, 256, 0, stream>>>(Wi, Wo, Wfm, Wg, Wdec);
    pack_cols<<<1280, 256, 0, stream>>>(W1, 1280, W1p, 1280, 0, 1024, 1280);
    pack_cols<<<256, 256, 0, stream>>>(Wm, 2048, Wml, 2048, 0, L_, 2048);
    pack_cols<<<256, 256, 0, stream>>>(Wl, 2048, Wml + L_ * 2048, 2048, 0, L_, 2048);
    pack_cols<<<128, 256, 0, stream>>>(Wz, L_, Wzp, L_, 0, H_, L_);
    pack_xenc<<<3840, 256, 0, stream>>>(x_enc, lengths, xe);
    pack_xdec<<<1920, 256, 0, stream>>>(emb, tokens, xd);

    // ---- encoder: 15 fused GEMM+cell steps (M=2048, N=4096, K=1152) ----
    {
        const ushort* hc = hA; ushort* hn = hB;
        for (int t = 0; t < T_; ++t) {
            gemm_dbuf<<<dim3(32, 16), 256, 0, stream>>>(
                ALdEnc{ xe + (size_t)t * 2048 * 128, hc }, WLdEnc{ Wenc },
                EpiEnc{ b_f, b_b, lengths, t, cenc, hc, hn });
            const ushort* tmp = hn; hn = (ushort*)hc; hc = tmp;
        }
        // final h in hc
        gemm_dbuf<<<dim3(2, 8), 256, 0, stream>>>(
            ALdHid{ hc }, WLdPlain{ Wml, 2048 }, EpiStoreF32{ ml, 256 });
    }
    latent_ew<<<512, 256, 0, stream>>>(ml, bm, bl, eps, zp, &accs[3]);
    gemm_dbuf<<<dim3(8, 8), 256, 0, stream>>>(
        ALdPlain{ zp, 128, 128 }, WLdPlain{ Wzp, 128 }, EpiBiasBf16{ hdA, bz });

    // ---- decoder: 15 × (combined gates+W1 GEMM, then score/CE) ----
    {
        const ushort* dc = hdA; ushort* dn = hdB;
        for (int t = 0; t < T_; ++t) {
            gemm_dbuf<<<dim3(40, 8), 256, 0, stream>>>(
                ALdDec{ xd + (size_t)t * 1024 * 128, dc, zp }, WLdDec{ Wdec, W1p },
                EpiDec{ bi, bo, bf, bg, b1, cdec, dn, hid1 });
            score_loss<<<B_, 256, 0, stream>>>(hid1, W2, b2, tokens, lengths, t, accs);
            const ushort* tmp = dn; dn = (ushort*)dc; dc = tmp;
        }
    }

    finalize_k<<<1, 64, 0, stream>>>(accs, (float*)d_out);
}

// Round 4
// 1338.612 us; speedup vs baseline: 10.7658x; 1.3983x over previous
//
#include <hip/hip_runtime.h>
#include <math.h>

#define B_ 1024
#define T_ 15
#define E_ 128
#define H_ 1024
#define L_ 128
#define V_ 21

typedef __attribute__((ext_vector_type(8))) short bf16x8;
typedef __attribute__((ext_vector_type(4))) float f32x4;

__device__ __forceinline__ float sigf(float x) { return 1.0f / (1.0f + expf(-x)); }

__device__ __forceinline__ ushort f2bf(float f) {
    unsigned u = __float_as_uint(f);
    u += 0x7fffu + ((u >> 16) & 1u);
    return (ushort)(u >> 16);
}

__device__ __forceinline__ void gl_lds16(const ushort* g, ushort* l) {
    __builtin_amdgcn_global_load_lds(
        (const __attribute__((address_space(1))) void*)g,
        (__attribute__((address_space(3))) void*)l, 16, 0, 0);
}

// ================= double-buffered bf16 MFMA GEMM core =================
// Tile 128x128, BK=32, 4 waves (2x2), each wave 64x64 = 4x4 frags of 16x16x32.
// bn = blockIdx.x*128 + al.bn0 (bn0 lets a small launch target a bn segment).
template <class ALd, class WLd, class Epi>
__global__ __launch_bounds__(256) void gemm_dbuf(ALd al, WLd wl, Epi ep) {
    __shared__ ushort As[2 * 4096];
    __shared__ ushort Ws[2 * 4096];
    const int tid = threadIdx.x;
    const int lane = tid & 63;
    const int w = tid >> 6;
    const int wr = w >> 1, wc = w & 1;
    const int bn = blockIdx.x * 128 + al.bn0;
    const int bm = blockIdx.y * 128;
    const int srow = tid >> 2, scol = (tid & 3) * 8;
    const int frow = lane & 15, fk = (lane >> 4) * 8;
    const int K = al.kdim(bn);

    ushort* adst = As + w * 512;
    ushort* wdst = Ws + w * 512;

    f32x4 acc[4][4];
#pragma unroll
    for (int m = 0; m < 4; ++m)
#pragma unroll
        for (int n = 0; n < 4; ++n) acc[m][n] = (f32x4)0.0f;

    gl_lds16(al.addr(bn, bm + srow, scol), adst);
    gl_lds16(al.addr(bn, bm + 64 + srow, scol), adst + 2048);
    gl_lds16(wl.addr(bm, bn + srow, scol), wdst);
    gl_lds16(wl.addr(bm, bn + 64 + srow, scol), wdst + 2048);
    __syncthreads();

    const int nk = K >> 5;
    for (int kt = 0; kt < nk; ++kt) {
        const int cb = (kt & 1) * 4096;
        const ushort* asp = As + cb + (wr * 64 + frow) * 32 + fk;
        const ushort* bsp = Ws + cb + (wc * 64 + frow) * 32 + fk;
        bf16x8 af[4], bw[4];
#pragma unroll
        for (int m = 0; m < 4; ++m) af[m] = *(const bf16x8*)(asp + m * 512);
#pragma unroll
        for (int n = 0; n < 4; ++n) bw[n] = *(const bf16x8*)(bsp + n * 512);
        if (kt + 1 < nk) {
            const int k0 = (kt + 1) * 32;
            const int nb = ((kt + 1) & 1) * 4096;
            gl_lds16(al.addr(bn, bm + srow, k0 + scol), As + nb + w * 512);
            gl_lds16(al.addr(bn, bm + 64 + srow, k0 + scol), As + nb + 2048 + w * 512);
            gl_lds16(wl.addr(bm, bn + srow, k0 + scol), Ws + nb + w * 512);
            gl_lds16(wl.addr(bm, bn + 64 + srow, k0 + scol), Ws + nb + 2048 + w * 512);
        }
#pragma unroll
        for (int m = 0; m < 4; ++m)
#pragma unroll
            for (int n = 0; n < 4; ++n)
                acc[m][n] = __builtin_amdgcn_mfma_f32_16x16x32_bf16(af[m], bw[n], acc[m][n], 0, 0, 0);
        __syncthreads();
    }
    ep(bm, bn, wr, wc, lane, acc);
}

// ================= loaders =================
struct ALdEnc {  // rows: dir*1024+b ; cols: [x_t(128) | h(1024)]
    const ushort* xe; const ushort* h; int bn0;
    __device__ int kdim(int) const { return 1152; }
    __device__ const ushort* addr(int, int row, int k) const {
        return (k < 128) ? xe + (size_t)row * 128 + k
                         : h + (size_t)row * 1024 + (k - 128);
    }
};
struct WLdEnc {  // [2][4096][1152] gate-interleaved, dir = bm>>10
    const ushort* W;
    __device__ const ushort* addr(int bm, int n, int k) const {
        return W + ((size_t)(bm >> 10) * 4096 + n) * 1152 + k;
    }
};
struct ALdDec {  // rows: b ; cols: [x_t | h | z]; bn>=5120 -> hid1prev (K=1024)
    const ushort* xd; const ushort* h; const ushort* z;
    const ushort* hid1prev; int bn0;
    __device__ int kdim(int bn) const {
        return bn < 4096 ? 1152 : (bn < 5120 ? 1280 : 1024);
    }
    __device__ const ushort* addr(int bn, int row, int k) const {
        if (bn >= 5120) return hid1prev + (size_t)row * 1024 + k;
        if (k < 128) return xd + (size_t)row * 128 + k;
        if (k < 1152) return h + (size_t)row * 1024 + (k - 128);
        return z + (size_t)row * 128 + (k - 1152);
    }
};
struct WLdDec {  // [4096][1152] gates | [1024][1280] W1 | [128][1024] W2pad
    const ushort* Wg4; const ushort* W1; const ushort* W2p;
    __device__ const ushort* addr(int, int n, int k) const {
        if (n < 4096) return Wg4 + (size_t)n * 1152 + k;
        if (n < 5120) return W1 + (size_t)(n - 4096) * 1280 + k;
        return W2p + (size_t)(n - 5120) * 1024 + k;
    }
};
struct ALdHid {  // hidden = [h_f | h_b]
    const ushort* hF; int bn0;
    __device__ int kdim(int) const { return 2048; }
    __device__ const ushort* addr(int, int row, int k) const {
        return hF + ((size_t)((k >> 10) << 10) + row) * 1024 + (k & 1023);
    }
};
struct ALdPlain {
    const ushort* A; int ld; int K; int bn0;
    __device__ int kdim(int) const { return K; }
    __device__ const ushort* addr(int, int row, int k) const { return A + (size_t)row * ld + k; }
};
struct WLdPlain {
    const ushort* W; int ld;
    __device__ const ushort* addr(int, int n, int k) const { return W + (size_t)n * ld + k; }
};

// ================= epilogues =================
struct EpiEnc {  // fused encoder LSTM cell, gate-interleaved: frag n = gate n (i,f,g,o)
    const float* b_f; const float* b_b; const int* len; int t;
    float* c; const ushort* hc; ushort* hn;
    __device__ void operator()(int bm, int bn, int wr, int wc, int lane,
                               f32x4 (&acc)[4][4]) const {
        const int j = ((bn >> 6) + wc) * 16 + (lane & 15);
        const int rbase = bm + wr * 64 + ((lane >> 4) << 2);
#pragma unroll
        for (int m = 0; m < 4; ++m) {
#pragma unroll
            for (int r = 0; r < 4; ++r) {
                const int row = rbase + m * 16 + r;
                const int b = row & 1023;
                const float* bias = (row >> 10) ? b_b : b_f;
                const size_t o = (size_t)row * 1024 + j;
                if (t < len[b]) {
                    float gi = acc[m][0][r] + bias[j];
                    float gf = acc[m][1][r] + bias[1024 + j];
                    float gg = acc[m][2][r] + bias[2048 + j];
                    float go = acc[m][3][r] + bias[3072 + j];
                    float nc = sigf(gf) * c[o] + sigf(gi) * tanhf(gg);
                    c[o] = nc;
                    hn[o] = f2bf(sigf(go) * tanhf(nc));
                } else {
                    hn[o] = hc[o];
                }
            }
        }
    }
};

struct EpiDec {
    const float *bi, *bo, *bfv, *bg, *b1, *b2;
    float* c; ushort* hn; ushort* hid1cur;
    const int* tokens; const int* len; int t;
    float* accs;
    __device__ void operator()(int bm, int bn, int wr, int wc, int lane,
                               f32x4 (&acc)[4][4]) const {
        const int rbase = bm + wr * 64 + ((lane >> 4) << 2);
        if (bn < 4096) {            // fused decoder LSTM cell (i,o,f,g)
            const int j = ((bn >> 6) + wc) * 16 + (lane & 15);
#pragma unroll
            for (int m = 0; m < 4; ++m) {
#pragma unroll
                for (int r = 0; r < 4; ++r) {
                    const int b = rbase + m * 16 + r;
                    const size_t o = (size_t)b * 1024 + j;
                    float gi = sigf(acc[m][0][r] + bi[j]);
                    float go = sigf(acc[m][1][r] + bo[j]);
                    float gf = sigf(acc[m][2][r] + bfv[j]);
                    float gg = tanhf(acc[m][3][r] + bg[j]);
                    float nc = gf * c[o] + gi * gg;
                    c[o] = nc;
                    hn[o] = f2bf(go * tanhf(nc));
                }
            }
        } else if (bn < 5120) {     // hid1 = relu(ah@W1^T + b1), bf16
            const int cb = (bn - 4096) + wc * 64;
#pragma unroll
            for (int m = 0; m < 4; ++m)
#pragma unroll
                for (int n = 0; n < 4; ++n) {
                    const int col = cb + n * 16 + (lane & 15);
#pragma unroll
                    for (int r = 0; r < 4; ++r)
                        hid1cur[(size_t)(rbase + m * 16 + r) * 1024 + col] =
                            f2bf(fmaxf(acc[m][n][r] + b1[col], 0.0f));
                }
        } else {                    // scores(t-1): CE/argmax, wave-parallel
            if (wc != 0) return;
            const int ts = t - 1;
            const int col0 = lane & 15;
            const bool v1ok = col0 < (V_ - 16);   // cols 16..20
            const float b2v0 = b2[col0];
            const float b2v1 = v1ok ? b2[16 + col0] : 0.0f;
            float ce_loc = 0.f, cor_loc = 0.f, msk_loc = 0.f;
#pragma unroll
            for (int m = 0; m < 4; ++m) {
#pragma unroll
                for (int r = 0; r < 4; ++r) {
                    const int b = rbase + m * 16 + r;
                    const int lb = len[b];
                    float v0 = acc[m][0][r] + b2v0;
                    float v1 = v1ok ? (acc[m][1][r] + b2v1) : -1e30f;
                    float mv; int mi;
                    if (v1 > v0) { mv = v1; mi = 16 + col0; } else { mv = v0; mi = col0; }
#pragma unroll
                    for (int s = 1; s < 16; s <<= 1) {
                        float ov = __shfl_xor(mv, s);
                        int oi = __shfl_xor(mi, s);
                        if (ov > mv || (ov == mv && oi < mi)) { mv = ov; mi = oi; }
                    }
                    float se = expf(v0 - mv) + (v1ok ? expf(v1 - mv) : 0.0f);
#pragma unroll
                    for (int s = 1; s < 16; s <<= 1) se += __shfl_xor(se, s);
                    float lse = mv + logf(se);
                    int tgt = (ts < lb) ? tokens[b * T_ + ts] : 0;
                    int srcl = (lane & 48) | (tgt & 15);
                    float sv0 = __shfl(v0, srcl);
                    float sv1 = __shfl(v1, srcl);
                    float stgt = (tgt < 16) ? sv0 : sv1;
                    if (ts <= lb && col0 == 0) {
                        ce_loc += lse - stgt;
                        cor_loc += (mi == tgt) ? 1.0f : 0.0f;
                        msk_loc += 1.0f;
                    }
                }
            }
            float ce = __shfl(ce_loc, 0) + __shfl(ce_loc, 16) + __shfl(ce_loc, 32) + __shfl(ce_loc, 48);
            float co = __shfl(cor_loc, 0) + __shfl(cor_loc, 16) + __shfl(cor_loc, 32) + __shfl(cor_loc, 48);
            float mk = __shfl(msk_loc, 0) + __shfl(msk_loc, 16) + __shfl(msk_loc, 32) + __shfl(msk_loc, 48);
            if (lane == 0) {
                atomicAdd(&accs[0], ce);
                atomicAdd(&accs[1], co);
                atomicAdd(&accs[2], mk);
            }
        }
    }
};

struct EpiStoreF32 {
    float* out; int ldc;
    __device__ void operator()(int bm, int bn, int wr, int wc, int lane,
                               f32x4 (&acc)[4][4]) const {
        const int rbase = bm + wr * 64 + ((lane >> 4) << 2);
        const int cbase = bn + wc * 64 + (lane & 15);
#pragma unroll
        for (int m = 0; m < 4; ++m)
#pragma unroll
            for (int n = 0; n < 4; ++n)
#pragma unroll
                for (int r = 0; r < 4; ++r)
                    out[(size_t)(rbase + m * 16 + r) * ldc + cbase + n * 16] = acc[m][n][r];
    }
};
struct EpiBiasBf16 {
    ushort* out; const float* bias;
    __device__ void operator()(int bm, int bn, int wr, int wc, int lane,
                               f32x4 (&acc)[4][4]) const {
        const int rbase = bm + wr * 64 + ((lane >> 4) << 2);
        const int cbase = bn + wc * 64 + (lane & 15);
#pragma unroll
        for (int m = 0; m < 4; ++m)
#pragma unroll
            for (int n = 0; n < 4; ++n) {
                const int col = cbase + n * 16;
#pragma unroll
                for (int r = 0; r < 4; ++r)
                    out[(size_t)(rbase + m * 16 + r) * 1024 + col] = f2bf(acc[m][n][r] + bias[col]);
            }
    }
};

// ================= packing / elementwise =================
__global__ void pack_cols(const float* __restrict__ src, int src_ld,
                          ushort* __restrict__ dst, int dst_ld, int dcol0,
                          int rows, int cols) {
    int i = blockIdx.x * 256 + threadIdx.x;
    int c4cnt = cols >> 2;
    if (i >= rows * c4cnt) return;
    int r = i / c4cnt, c4 = (i - r * c4cnt) * 4;
    float4 v = *(const float4*)(src + (size_t)r * src_ld + c4);
    ushort4 o = { f2bf(v.x), f2bf(v.y), f2bf(v.z), f2bf(v.w) };
    *(ushort4*)(dst + (size_t)r * dst_ld + dcol0 + c4) = o;
}

__global__ void pack_gates_enc(const float* __restrict__ Wih_f, const float* __restrict__ Whh_f,
                               const float* __restrict__ Wih_b, const float* __restrict__ Whh_b,
                               ushort* __restrict__ dst) {
    int i = blockIdx.x * 256 + threadIdx.x;   // 2*4096*288
    if (i >= 2 * 4096 * 288) return;
    int c4 = (i % 288) * 4;
    int p = (i / 288) & 4095;
    int dir = i / (288 * 4096);
    int j = ((p >> 6) << 4) + (p & 15);
    int g = (p >> 4) & 3;
    int srow = g * 1024 + j;
    float4 v;
    if (c4 < 128) {
        const float* s = dir ? Wih_b : Wih_f;
        v = *(const float4*)(s + (size_t)srow * 128 + c4);
    } else {
        const float* s = dir ? Whh_b : Whh_f;
        v = *(const float4*)(s + (size_t)srow * 1024 + (c4 - 128));
    }
    ushort4 o = { f2bf(v.x), f2bf(v.y), f2bf(v.z), f2bf(v.w) };
    *(ushort4*)(dst + ((size_t)dir * 4096 + p) * 1152 + c4) = o;
}

__global__ void pack_gates_dec(const float* __restrict__ Wi, const float* __restrict__ Wo,
                               const float* __restrict__ Wf, const float* __restrict__ Wg,
                               ushort* __restrict__ dst) {
    int i = blockIdx.x * 256 + threadIdx.x;   // 4096*288
    if (i >= 4096 * 288) return;
    int c4 = (i % 288) * 4;
    int p = i / 288;
    int j = ((p >> 6) << 4) + (p & 15);
    int g = (p >> 4) & 3;
    const float* s = (g == 0) ? Wi : (g == 1) ? Wo : (g == 2) ? Wf : Wg;
    float4 v = *(const float4*)(s + (size_t)j * 1152 + c4);
    ushort4 o = { f2bf(v.x), f2bf(v.y), f2bf(v.z), f2bf(v.w) };
    *(ushort4*)(dst + (size_t)p * 1152 + c4) = o;
}

__global__ void pack_w2(const float* __restrict__ W2, ushort* __restrict__ dst) {
    int i = blockIdx.x * 256 + threadIdx.x;   // 128*256
    if (i >= 128 * 256) return;
    int r = i >> 8, c4 = (i & 255) * 4;
    ushort4 o = { 0, 0, 0, 0 };
    if (r < V_) {
        float4 v = *(const float4*)(W2 + (size_t)r * 1024 + c4);
        o = ushort4{ f2bf(v.x), f2bf(v.y), f2bf(v.z), f2bf(v.w) };
    }
    *(ushort4*)(dst + (size_t)r * 1024 + c4) = o;
}

__global__ void pack_xenc(const float* __restrict__ xenc, const int* __restrict__ len,
                          ushort* __restrict__ xe) {
    int i = blockIdx.x * 256 + threadIdx.x;   // 15*2048*32
    if (i >= 15 * 2048 * 32) return;
    int c4 = (i & 31) * 4;
    int r = (i >> 5) & 2047;
    int t = i >> 16;
    int dir = r >> 10, b = r & 1023;
    int tt = t;
    if (dir) {
        int ri = len[b] - 1 - t;
        tt = ri < 0 ? 0 : (ri > T_ - 1 ? T_ - 1 : ri);
    }
    float4 v = *(const float4*)(xenc + ((size_t)b * T_ + tt) * 128 + c4);
    ushort4 o = { f2bf(v.x), f2bf(v.y), f2bf(v.z), f2bf(v.w) };
    *(ushort4*)(xe + ((size_t)t * 2048 + r) * 128 + c4) = o;
}

__global__ void pack_xdec(const float* __restrict__ emb, const int* __restrict__ tokens,
                          ushort* __restrict__ xd) {
    int i = blockIdx.x * 256 + threadIdx.x;   // 15*1024*32
    if (i >= 15 * 1024 * 32) return;
    int c4 = (i & 31) * 4;
    int b = (i >> 5) & 1023;
    int t = i >> 15;
    ushort4 o = { 0, 0, 0, 0 };
    if (t > 0) {
        int tok = tokens[(size_t)b * T_ + (t - 1)];
        float4 v = *(const float4*)(emb + (size_t)tok * 128 + c4);
        o = ushort4{ f2bf(v.x), f2bf(v.y), f2bf(v.z), f2bf(v.w) };
    }
    *(ushort4*)(xd + ((size_t)t * 1024 + b) * 128 + c4) = o;
}

__global__ void init_zero(float* cenc, float* cdec, ushort* hA, float* accs) {
    int i = blockIdx.x * 256 + threadIdx.x;
    if (i < 2 * 1024 * 1024) { cenc[i] = 0.0f; hA[i] = 0; }
    if (i < 1024 * 1024) cdec[i] = 0.0f;
    if (i < 8) accs[i] = 0.0f;
}

__global__ void latent_ew(const float* __restrict__ ml, const float* __restrict__ bmv,
                          const float* __restrict__ blv, const float* __restrict__ eps,
                          ushort* __restrict__ zp, float* __restrict__ klacc) {
    int idx = blockIdx.x * 256 + threadIdx.x;
    int b = idx >> 7, l = idx & (L_ - 1);
    float mean = ml[(size_t)b * 256 + l] + bmv[l];
    float logv = ml[(size_t)b * 256 + L_ + l] + blv[l];
    zp[idx] = f2bf(eps[idx] * expf(0.5f * logv) + mean);
    float part = 1.0f + logv - mean * mean - expf(logv);
    for (int off = 32; off; off >>= 1) part += __shfl_down(part, off);
    __shared__ float s[4];
    int lane = threadIdx.x & 63, wv = threadIdx.x >> 6;
    if (lane == 0) s[wv] = part;
    __syncthreads();
    if (threadIdx.x == 0) atomicAdd(klacc, s[0] + s[1] + s[2] + s[3]);
}

__global__ void finalize_k(const float* accs, float* out) {
    if (threadIdx.x == 0 && blockIdx.x == 0) {
        float kl = -0.5f * accs[3] / (float)B_;
        float amino = accs[0] / (float)B_;
        out[0] = amino + 0.1f * kl;
        out[1] = amino;
        out[2] = kl;
        out[3] = accs[1] / accs[2];
    }
}

// ================= host =================
extern "C" void kernel_launch(void* const* d_in, const int* in_sizes, int n_in,
                              void* d_out, int out_size, void* d_ws, size_t ws_size,
                              hipStream_t stream) {
    (void)in_sizes; (void)n_in; (void)out_size; (void)ws_size;
    const float* x_enc  = (const float*)d_in[0];
    const int*   tokens = (const int*)d_in[1];
    const int*   lengths= (const int*)d_in[2];
    const float* eps    = (const float*)d_in[3];
    const float* emb    = (const float*)d_in[4];
    const float* Wih_f  = (const float*)d_in[5];
    const float* Whh_f  = (const float*)d_in[6];
    const float* b_f    = (const float*)d_in[7];
    const float* Wih_b  = (const float*)d_in[8];
    const float* Whh_b  = (const float*)d_in[9];
    const float* b_b    = (const float*)d_in[10];
    const float* Wm     = (const float*)d_in[11];
    const float* bm     = (const float*)d_in[12];
    const float* Wl     = (const float*)d_in[13];
    const float* bl     = (const float*)d_in[14];
    const float* Wz     = (const float*)d_in[15];
    const float* bz     = (const float*)d_in[16];
    const float* Wi     = (const float*)d_in[17];
    const float* bi     = (const float*)d_in[18];
    const float* Wo     = (const float*)d_in[19];
    const float* bo     = (const float*)d_in[20];
    const float* Wfm    = (const float*)d_in[21];
    const float* bf     = (const float*)d_in[22];
    const float* Wg     = (const float*)d_in[23];
    const float* bg     = (const float*)d_in[24];
    const float* W1     = (const float*)d_in[25];
    const float* b1     = (const float*)d_in[26];
    const float* W2     = (const float*)d_in[27];
    const float* b2     = (const float*)d_in[28];

    float*  cenc = (float*)d_ws;                    // 2M f32
    float*  cdec = cenc + 2 * 1024 * 1024;          // 1M f32
    float*  ml   = cdec + 1024 * 1024;              // 256K f32
    float*  accs = ml + 1024 * 256;                 // 8 (+pad 64)
    ushort* hA   = (ushort*)(accs + 64);            // 2M
    ushort* hB   = hA + 2 * 1024 * 1024;
    ushort* hdA  = hB + 2 * 1024 * 1024;            // 1M
    ushort* hdB  = hdA + 1024 * 1024;
    ushort* h1A  = hdB + 1024 * 1024;               // 1M
    ushort* h1B  = h1A + 1024 * 1024;
    ushort* zp   = h1B + 1024 * 1024;               // 128K
    ushort* xe   = zp + 1024 * 128;                 // 15*2048*128
    ushort* xd   = xe + 15 * 2048 * 128;            // 15*1024*128
    ushort* Wenc = xd + 15 * 1024 * 128;            // 2*4096*1152
    ushort* Wdec = Wenc + 2 * 4096 * 1152;          // 4096*1152
    ushort* W1p  = Wdec + 4096 * 1152;              // 1024*1280
    ushort* Wml  = W1p + 1024 * 1280;               // 256*2048
    ushort* Wzp  = Wml + 256 * 2048;                // 1024*128
    ushort* W2p  = Wzp + 1024 * 128;                // 128*1024

    init_zero<<<8192, 256, 0, stream>>>(cenc, cdec, hA, accs);
    pack_gates_enc<<<9216, 256, 0, stream>>>(Wih_f, Whh_f, Wih_b, Whh_b, Wenc);
    pack_gates_dec<<<4608, 256, 0, stream>>>(Wi, Wo, Wfm, Wg, Wdec);
    pack_cols<<<1280, 256, 0, stream>>>(W1, 1280, W1p, 1280, 0, 1024, 1280);
    pack_cols<<<256, 256, 0, stream>>>(Wm, 2048, Wml, 2048, 0, L_, 2048);
    pack_cols<<<256, 256, 0, stream>>>(Wl, 2048, Wml + L_ * 2048, 2048, 0, L_, 2048);
    pack_cols<<<128, 256, 0, stream>>>(Wz, L_, Wzp, L_, 0, H_, L_);
    pack_w2<<<128, 256, 0, stream>>>(W2, W2p);
    pack_xenc<<<3840, 256, 0, stream>>>(x_enc, lengths, xe);
    pack_xdec<<<1920, 256, 0, stream>>>(emb, tokens, xd);

    // ---- encoder ----
    {
        const ushort* hc = hA; ushort* hn = hB;
        for (int t = 0; t < T_; ++t) {
            gemm_dbuf<<<dim3(32, 16), 256, 0, stream>>>(
                ALdEnc{ xe + (size_t)t * 2048 * 128, hc, 0 }, WLdEnc{ Wenc },
                EpiEnc{ b_f, b_b, lengths, t, cenc, hc, hn });
            const ushort* tmp = hn; hn = (ushort*)hc; hc = tmp;
        }
        gemm_dbuf<<<dim3(2, 8), 256, 0, stream>>>(
            ALdHid{ hc, 0 }, WLdPlain{ Wml, 2048 }, EpiStoreF32{ ml, 256 });
    }
    latent_ew<<<512, 256, 0, stream>>>(ml, bm, bl, eps, zp, &accs[3]);
    gemm_dbuf<<<dim3(8, 8), 256, 0, stream>>>(
        ALdPlain{ zp, 128, 128, 0 }, WLdPlain{ Wzp, 128 }, EpiBiasBf16{ hdA, bz });

    // ---- decoder: scores(t-1) fused as extra bn segment ----
    {
        const ushort* dc = hdA; ushort* dn = hdB;
        for (int t = 0; t < T_; ++t) {
            ushort* h1c = (t & 1) ? h1B : h1A;
            const ushort* h1p = (t & 1) ? h1A : h1B;
            dim3 grid(t == 0 ? 40 : 41, 8);
            gemm_dbuf<<<grid, 256, 0, stream>>>(
                ALdDec{ xd + (size_t)t * 1024 * 128, dc, zp, h1p, 0 },
                WLdDec{ Wdec, W1p, W2p },
                EpiDec{ bi, bo, bf, bg, b1, b2, cdec, dn, h1c, tokens, lengths, t, accs });
            const ushort* tmp = dn; dn = (ushort*)dc; dc = tmp;
        }
        const ushort* h1p14 = ((T_ - 1) & 1) ? h1B : h1A;  // hid1 written at t=14
        gemm_dbuf<<<dim3(1, 8), 256, 0, stream>>>(
            ALdDec{ xd, dc, zp, h1p14, 5120 },
            WLdDec{ Wdec, W1p, W2p },
            EpiDec{ bi, bo, bf, bg, b1, b2, cdec, hdB, h1B, tokens, lengths, T_, accs });
    }

    finalize_k<<<1, 64, 0, stream>>>(accs, (float*)d_out);
}